// Round 4
// baseline (285.470 us; speedup 1.0000x reference)
//
#include <hip/hip_runtime.h>
#include <hip/hip_cooperative_groups.h>

namespace cg = cooperative_groups;

// Problem constants
#define SRC_N   (512 * 512)
#define IMG_W   1024
#define IMG_HW  (1024 * 1024)
#define BATCH   4

#define CHUNKS_PER_B   128
#define K1_BLOCKS      (BATCH * CHUNKS_PER_B)    // 512
#define PTS_PER_CHUNK  2048
// Bins: 0..255 = 4-row bands (y-interior pixels); 256..287 = row-0 px-segments
// (32 px each); 288..319 = row-1023 px-segments. Corners -> LDS side path.
#define NBINS          320
#define PF_E           (NBINS + 1)
#define SENT           0xFFFFFFFFu

#define EDGE_BLOCKS    (BATCH * 64)              // 256 edge jobs
#define BAND_BLOCKS    (BATCH * 256)             // 1024 band jobs

typedef float nfloat4 __attribute__((ext_vector_type(4)));

__device__ __forceinline__ nfloat4 ntload4(const float* p) {
    return __builtin_nontemporal_load((const nfloat4*)p);
}

// ws layout
#define STAGED_BYTES ((size_t)K1_BLOCKS * PTS_PER_CHUNK * 16)          // 16 MB
#define PF_OFF       STAGED_BYTES
#define PF_BYTES     ((size_t)BATCH * PF_E * CHUNKS_PER_B * 4)         // 657 KB
#define CO_OFF       ((PF_OFF + PF_BYTES + 255) & ~(size_t)255)
#define CO_BYTES     ((size_t)K1_BLOCKS * 12 * 4)                      // 24 KB

// ---------------------------------------------------------------------------
// Phase A: classify + per-chunk bin (identical logic to the proven K1).
// LDS is carved from the caller's 48KB acc buffer:
//   s_stage = acc[0..8191] (32KB float4), s_hist = acc[8192..], s_cur,
//   s_wsum, s_corner — total 35.7KB.
// ---------------------------------------------------------------------------
__device__ __forceinline__ void phaseA(
    const int blk, const int t,
    const float* __restrict__ uv, const float* __restrict__ pos,
    float4* __restrict__ staged, unsigned* __restrict__ prefixT,
    float* __restrict__ corner_out,
    float4* s_stage, unsigned* s_hist, unsigned* s_cur,
    unsigned* s_wsum, float* s_corner)
{
    const int b     = blk >> 7;
    const int chunk = blk & (CHUNKS_PER_B - 1);
    const int lane  = t & 63;
    const int wave  = t >> 6;

    s_hist[t] = 0;
    if (t < 96) s_corner[t] = 0.0f;
    __syncthreads();                                               // B1

    const float* uvb = uv  + (size_t)b * 14 * SRC_N;
    const float* pb  = pos + (size_t)b * 3  * SRC_N;
    const int n0 = chunk * PTS_PER_CHUNK + t * 4;

    const nfloat4 pxv = ntload4(&pb [n0]);
    const nfloat4 pyv = ntload4(&pb [SRC_N + n0]);
    const nfloat4 ux  = ntload4(&uvb[n0]);
    const nfloat4 uy  = ntload4(&uvb[SRC_N + n0]);
    const nfloat4 ov  = ntload4(&uvb[10 * SRC_N + n0]);
    const nfloat4 rv  = ntload4(&uvb[11 * SRC_N + n0]);
    const nfloat4 gv  = ntload4(&uvb[12 * SRC_N + n0]);
    const nfloat4 bv  = ntload4(&uvb[13 * SRC_N + n0]);

    const float X[4]  = {pxv.x + ux.x, pxv.y + ux.y, pxv.z + ux.z, pxv.w + ux.w};
    const float Y[4]  = {pyv.x + uy.x, pyv.y + uy.y, pyv.z + uy.z, pyv.w + uy.w};
    const float O[4]  = {ov.x, ov.y, ov.z, ov.w};
    const float CR[4] = {rv.x, rv.y, rv.z, rv.w};
    const float CG[4] = {gv.x, gv.y, gv.z, gv.w};
    const float CB[4] = {bv.x, bv.y, bv.z, bv.w};

    unsigned packed[4];
    float R[4], G[4], B[4];

#pragma unroll
    for (int j = 0; j < 4; ++j) {
        int px = (int)((X[j] + 1.0f) * 512.0f);    // truncating cast + clamp
        int py = (int)((Y[j] + 1.0f) * 512.0f);
        px = min(max(px, 0), IMG_W - 1);
        py = min(max(py, 0), IMG_W - 1);

        const float opac = 1.0f / (1.0f + __expf(-O[j]));
        R[j] = CR[j] * opac; G[j] = CG[j] * opac; B[j] = CB[j] * opac;

        const bool xe = (px == 0) | (px == IMG_W - 1);
        const bool ye = (py == 0) | (py == IMG_W - 1);
        if (xe & ye) {
            const int ci = ((py != 0) ? 2 : 0) + ((px != 0) ? 1 : 0);
            const int base = wave * 12 + ci * 3;
            atomicAdd(&s_corner[base + 0], R[j]);
            atomicAdd(&s_corner[base + 1], G[j]);
            atomicAdd(&s_corner[base + 2], B[j]);
            packed[j] = SENT;
        } else {
            int bin;
            if (ye) bin = 256 + ((py != 0) ? 32 : 0) + (px >> 5);
            else    bin = py >> 2;
            atomicAdd(&s_hist[bin], 1u);
            packed[j] = ((unsigned)bin << 12) | ((unsigned)(py & 3) << 10)
                      | (unsigned)px;
        }
    }
    __syncthreads();                                               // B2

    // hierarchical exclusive scan of s_hist[0..511]
    const unsigned h = s_hist[t];
    unsigned incl = h;
#pragma unroll
    for (int off = 1; off < 64; off <<= 1) {
        const unsigned n = __shfl_up(incl, off, 64);
        if (lane >= off) incl += n;
    }
    if (lane == 63) s_wsum[wave] = incl;
    __syncthreads();                                               // B3
    unsigned woff = 0;
#pragma unroll
    for (int w = 0; w < 8; ++w) woff += (w < wave) ? s_wsum[w] : 0u;
    const unsigned excl = woff + incl - h;

    if (t < NBINS) s_cur[t] = excl;
    if (t <= NBINS)                        // transposed: [b][bin][chunk]
        prefixT[((size_t)(b * PF_E + t)) * CHUNKS_PER_B + chunk] = excl;
    if (t < 12) {
        float s = 0.0f;
#pragma unroll
        for (int w = 0; w < 8; ++w) s += s_corner[w * 12 + t];
        corner_out[blk * 12 + t] = s;
    }
    __syncthreads();                                               // B4

    // cur-ordered scatter into LDS staging
#pragma unroll
    for (int j = 0; j < 4; ++j) {
        if (packed[j] != SENT) {
            const int bin = packed[j] >> 12;
            const unsigned p = atomicAdd(&s_cur[bin], 1u);
            s_stage[p] = make_float4(__uint_as_float(packed[j]), R[j], G[j], B[j]);
        }
    }
    __syncthreads();                                               // B5

    // fully coalesced LDS -> global copy
    float4* pbase = staged + (size_t)blk * PTS_PER_CHUNK;
#pragma unroll
    for (int k = 0; k < 4; ++k)
        pbase[k * 512 + t] = s_stage[k * 512 + t];
}

// ---------------------------------------------------------------------------
// Edge job: (b, row in {0,1023}, 32px segment) — accumulates edge payloads +
// corner partials and writes the final output row directly.
// ---------------------------------------------------------------------------
__device__ __forceinline__ void edge_job(
    const int blk, const int t, float* acc, unsigned* rs, unsigned* re,
    const float4* __restrict__ staged, const unsigned* __restrict__ prefixT,
    const float* __restrict__ corner_out, float* __restrict__ out)
{
    const int b   = blk >> 6;
    const int row = (blk >> 5) & 1;
    const int seg = blk & 31;
    const int bin = 256 + row * 32 + seg;

    if (t < 96) acc[t] = 0.0f;
    if (t < 128)      rs[t]       = prefixT[((size_t)(b * PF_E + bin)) * 128 + t];
    else if (t < 256) re[t - 128] = prefixT[((size_t)(b * PF_E + bin + 1)) * 128 + (t - 128)];
    __syncthreads();

    const int chunk = t >> 2;
    const int sub   = t & 3;
    const float4* pbase = staged + (size_t)(b * 128 + chunk) * PTS_PER_CHUNK;
    for (unsigned i = rs[chunk] + sub; i < re[chunk]; i += 4) {
        const float4 v = pbase[i];
        const int lx = (int)(__float_as_uint(v.x) & 1023u) - seg * 32;
        atomicAdd(&acc[lx],      v.y);
        atomicAdd(&acc[32 + lx], v.z);
        atomicAdd(&acc[64 + lx], v.w);
    }

    if (((seg == 0) | (seg == 31)) & (t < 128)) {
        const int ci = row * 2 + ((seg == 31) ? 1 : 0);
        const int lx = (seg == 31) ? 31 : 0;
        const float* cp = corner_out + (size_t)(b * 128 + t) * 12 + ci * 3;
        atomicAdd(&acc[lx],      cp[0]);
        atomicAdd(&acc[32 + lx], cp[1]);
        atomicAdd(&acc[64 + lx], cp[2]);
    }
    __syncthreads();

    if (t < 96) {
        const int c  = t >> 5, lx = t & 31;
        const size_t py = row ? (IMG_W - 1) : 0;
        const float v = acc[c * 32 + lx];
        out[((size_t)b * 3 + c) * IMG_HW + py * IMG_W + seg * 32 + lx] =
            fminf(fmaxf(v, 0.f), 1.f);
    }
}

// ---------------------------------------------------------------------------
// Band job: (b, 4-row band) — gather sorted runs from 128 chunks, LDS-atomic
// accumulate, linear clipped NT stores. Bands 0/255 skip rows 0/1023 (owned
// by edge jobs).
// ---------------------------------------------------------------------------
__device__ __forceinline__ void band_job(
    const int job, const int t, float* acc, unsigned* rs, unsigned* re,
    const float4* __restrict__ staged, const unsigned* __restrict__ prefixT,
    float* __restrict__ out)
{
    const int b    = job >> 8;
    const int band = job & 255;
    float4* acc4 = (float4*)acc;

    const float4 z4 = make_float4(0.f, 0.f, 0.f, 0.f);
#pragma unroll
    for (int i = 0; i < 6; ++i) acc4[i * 512 + t] = z4;
    if (t < 128)      rs[t]       = prefixT[((size_t)(b * PF_E + band)) * 128 + t];
    else if (t < 256) re[t - 128] = prefixT[((size_t)(b * PF_E + band + 1)) * 128 + (t - 128)];
    __syncthreads();

    const int chunk = t >> 2;
    const int sub   = t & 3;
    const float4* pbase = staged + (size_t)(b * 128 + chunk) * PTS_PER_CHUNK;
    for (unsigned i = rs[chunk] + sub; i < re[chunk]; i += 4) {
        const float4 v = pbase[i];
        const unsigned key = __float_as_uint(v.x);
        const unsigned idx = ((key >> 10) & 3u) * 1024 + (key & 1023u);
        atomicAdd(&acc[idx],        v.y);
        atomicAdd(&acc[4096 + idx], v.z);
        atomicAdd(&acc[8192 + idx], v.w);
    }
    __syncthreads();

    float* ob = out + (size_t)b * 3 * IMG_HW + (size_t)band * 4096;
    const int skip_ly = (band == 0) ? 0 : ((band == 255) ? 3 : -1);
#pragma unroll
    for (int c = 0; c < 3; ++c) {
        nfloat4* dst = (nfloat4*)(ob + (size_t)c * IMG_HW);
#pragma unroll
        for (int k = 0; k < 2; ++k) {
            const int f = k * 512 + t;
            if ((f >> 8) == skip_ly) continue;   // wave-uniform predicate
            float4 v = acc4[c * 1024 + f];
            nfloat4 w;
            w.x = fminf(fmaxf(v.x, 0.f), 1.f);
            w.y = fminf(fmaxf(v.y, 0.f), 1.f);
            w.z = fminf(fmaxf(v.z, 0.f), 1.f);
            w.w = fminf(fmaxf(v.w, 0.f), 1.f);
            __builtin_nontemporal_store(w, &dst[f]);
        }
    }
}

// ---------------------------------------------------------------------------
// Fused cooperative kernel: 512 blocks x 512 threads, 2 blocks/CU (49KB LDS,
// VGPR<=128 via launch_bounds) -> exactly co-resident. Phase A = per-chunk
// classify/bin; grid.sync(); Phase B = 256 edge jobs (blocks 0..255) + 1024
// band jobs (2 per block). Removes the inter-kernel launch gap and gives a
// single >42us dispatch so rocprof's top-5 finally shows OUR counters.
// ---------------------------------------------------------------------------
__global__ void __launch_bounds__(512, 4)
fused_kernel(const float* __restrict__ uv, const float* __restrict__ pos,
             float4* __restrict__ staged, unsigned* __restrict__ prefixT,
             float* __restrict__ corner_out, float* __restrict__ out)
{
    __shared__ __align__(16) float acc[3 * 4096];   // 48KB, phase-shared
    __shared__ unsigned rs[128], re[128];
    const int blk = blockIdx.x;
    const int t   = threadIdx.x;

    phaseA(blk, t, uv, pos, staged, prefixT, corner_out,
           (float4*)acc,
           (unsigned*)(acc + 8192),     // s_hist[512]
           (unsigned*)(acc + 8704),     // s_cur[320]
           (unsigned*)(acc + 9024),     // s_wsum[8]
           acc + 9032);                 // s_corner[96]

    __threadfence();                    // release staged/prefixT/corner_out
    cg::this_grid().sync();

    if (blk < EDGE_BLOCKS) {
        edge_job(blk, t, acc, rs, re, staged, prefixT, corner_out, out);
        __syncthreads();
    }
    band_job(blk, t, acc, rs, re, staged, prefixT, out);
    __syncthreads();
    band_job(blk + 512, t, acc, rs, re, staged, prefixT, out);
}

// ---------------------------------------------------------------------------
// Fallback pair (proven round-3 path) in case cooperative launch is rejected.
// ---------------------------------------------------------------------------
__global__ void __launch_bounds__(512, 4)
bin_kernel(const float* __restrict__ uv, const float* __restrict__ pos,
           float4* __restrict__ staged, unsigned* __restrict__ prefixT,
           float* __restrict__ corner_out) {
    __shared__ __align__(16) float acc[3 * 4096];
    phaseA(blockIdx.x, threadIdx.x, uv, pos, staged, prefixT, corner_out,
           (float4*)acc, (unsigned*)(acc + 8192), (unsigned*)(acc + 8704),
           (unsigned*)(acc + 9024), acc + 9032);
}

__global__ void __launch_bounds__(512, 4)
render_kernel(const float4* __restrict__ staged, const unsigned* __restrict__ prefixT,
              const float* __restrict__ corner_out, float* __restrict__ out) {
    __shared__ __align__(16) float acc[3 * 4096];
    __shared__ unsigned rs[128], re[128];
    const int t = threadIdx.x;
    if (blockIdx.x < EDGE_BLOCKS) {
        edge_job(blockIdx.x, t, acc, rs, re, staged, prefixT, corner_out, out);
        return;
    }
    band_job(blockIdx.x - EDGE_BLOCKS, t, acc, rs, re, staged, prefixT, out);
}

extern "C" void kernel_launch(void* const* d_in, const int* in_sizes, int n_in,
                              void* d_out, int out_size, void* d_ws, size_t ws_size,
                              hipStream_t stream) {
    const float* uv  = (const float*)d_in[0];   // (4,14,512,512)
    const float* pos = (const float*)d_in[1];   // (4,3,512,512)
    float* out = (float*)d_out;                 // (4,3,1024,1024)

    char* ws = (char*)d_ws;
    float4*   staged     = (float4*)(ws);
    unsigned* prefixT    = (unsigned*)(ws + PF_OFF);
    float*    corner_out = (float*)(ws + CO_OFF);

    void* args[6] = {(void*)&uv, (void*)&pos, (void*)&staged,
                     (void*)&prefixT, (void*)&corner_out, (void*)&out};
    hipError_t err = hipLaunchCooperativeKernel((const void*)fused_kernel,
                                                dim3(K1_BLOCKS), dim3(512),
                                                args, 0, stream);
    if (err != hipSuccess) {
        // fallback: proven two-kernel path
        bin_kernel   <<<K1_BLOCKS, 512, 0, stream>>>(uv, pos, staged, prefixT,
                                                     corner_out);
        render_kernel<<<EDGE_BLOCKS + BAND_BLOCKS, 512, 0, stream>>>(staged, prefixT,
                                                                     corner_out, out);
    }
}

// Round 5
// 125.059 us; speedup vs baseline: 2.2827x; 2.2827x over previous
//
#include <hip/hip_runtime.h>

// Problem constants
#define SRC_N   (512 * 512)
#define IMG_W   1024
#define IMG_HW  (1024 * 1024)
#define BATCH   4

#define CHUNKS_PER_B   128
#define K1_BLOCKS      (BATCH * CHUNKS_PER_B)    // 512
#define PTS_PER_CHUNK  2048
// Bins: 0..255 = 4-row bands (y-interior pixels); 256..287 = row-0 px-segments
// (32 px each); 288..319 = row-1023 px-segments. Corners -> LDS side path.
#define NBINS          320
#define PF_E           (NBINS + 1)
#define SENT           0xFFFFFFFFu

#define EDGE_BLOCKS    (BATCH * 64)              // 256 edge jobs
#define BAND_BLOCKS    (BATCH * 256)             // 1024 band jobs

typedef float nfloat4 __attribute__((ext_vector_type(4)));

__device__ __forceinline__ nfloat4 ntload4(const float* p) {
    return __builtin_nontemporal_load((const nfloat4*)p);
}

// ws layout
#define STAGED_BYTES ((size_t)K1_BLOCKS * PTS_PER_CHUNK * 16)          // 16 MB
#define PF_OFF       STAGED_BYTES
#define PF_BYTES     ((size_t)BATCH * PF_E * CHUNKS_PER_B * 4)         // 657 KB
#define CO_OFF       ((PF_OFF + PF_BYTES + 255) & ~(size_t)255)
#define CO_BYTES     ((size_t)K1_BLOCKS * 12 * 4)                      // 24 KB

// ---------------------------------------------------------------------------
// K1: proven round-3 kernel, verbatim. Classify + per-chunk bin, hierarchical
// scan, per-wave corner slots, transposed prefix, LDS-staged sorted scatter,
// coalesced LDS->global copy. VGPR ~40, 36.7KB LDS, 2 blocks/CU (grid-limited).
// ---------------------------------------------------------------------------
__global__ void __launch_bounds__(512, 4)
bin_kernel(const float* __restrict__ uv, const float* __restrict__ pos,
           float4* __restrict__ staged, unsigned* __restrict__ prefixT,
           float* __restrict__ corner_out) {
    const int blk   = blockIdx.x;          // 0..511
    const int b     = blk >> 7;
    const int chunk = blk & (CHUNKS_PER_B - 1);
    const int t     = threadIdx.x;
    const int lane  = t & 63;
    const int wave  = t >> 6;              // 0..7

    __shared__ unsigned s_hist[512];       // bins 320..511 stay zero
    __shared__ unsigned s_cur[NBINS];
    __shared__ unsigned s_wsum[8];
    __shared__ float    s_corner[96];      // [wave][ci*3+c]
    __shared__ float4   s_stage[PTS_PER_CHUNK];   // 32KB bin-sorted staging

    s_hist[t] = 0;
    if (t < 96) s_corner[t] = 0.0f;
    __syncthreads();                                               // B1

    const float* uvb = uv  + (size_t)b * 14 * SRC_N;
    const float* pb  = pos + (size_t)b * 3  * SRC_N;
    const int n0 = chunk * PTS_PER_CHUNK + t * 4;

    // nontemporal: inputs are read exactly once; keep L2 for the staged buf
    const nfloat4 pxv = ntload4(&pb [n0]);
    const nfloat4 pyv = ntload4(&pb [SRC_N + n0]);
    const nfloat4 ux  = ntload4(&uvb[n0]);
    const nfloat4 uy  = ntload4(&uvb[SRC_N + n0]);
    const nfloat4 ov  = ntload4(&uvb[10 * SRC_N + n0]);
    const nfloat4 rv  = ntload4(&uvb[11 * SRC_N + n0]);
    const nfloat4 gv  = ntload4(&uvb[12 * SRC_N + n0]);
    const nfloat4 bv  = ntload4(&uvb[13 * SRC_N + n0]);

    const float X[4]  = {pxv.x + ux.x, pxv.y + ux.y, pxv.z + ux.z, pxv.w + ux.w};
    const float Y[4]  = {pyv.x + uy.x, pyv.y + uy.y, pyv.z + uy.z, pyv.w + uy.w};
    const float O[4]  = {ov.x, ov.y, ov.z, ov.w};
    const float CR[4] = {rv.x, rv.y, rv.z, rv.w};
    const float CG[4] = {gv.x, gv.y, gv.z, gv.w};
    const float CB[4] = {bv.x, bv.y, bv.z, bv.w};

    unsigned packed[4];
    float R[4], G[4], B[4];

#pragma unroll
    for (int j = 0; j < 4; ++j) {
        // truncating cast (matches .astype(int32)), then clamp
        int px = (int)((X[j] + 1.0f) * 512.0f);
        int py = (int)((Y[j] + 1.0f) * 512.0f);
        px = min(max(px, 0), IMG_W - 1);
        py = min(max(py, 0), IMG_W - 1);

        const float opac = 1.0f / (1.0f + __expf(-O[j]));
        R[j] = CR[j] * opac; G[j] = CG[j] * opac; B[j] = CB[j] * opac;

        const bool xe = (px == 0) | (px == IMG_W - 1);
        const bool ye = (py == 0) | (py == IMG_W - 1);
        if (xe & ye) {
            const int ci = ((py != 0) ? 2 : 0) + ((px != 0) ? 1 : 0);
            const int base = wave * 12 + ci * 3;
            atomicAdd(&s_corner[base + 0], R[j]);
            atomicAdd(&s_corner[base + 1], G[j]);
            atomicAdd(&s_corner[base + 2], B[j]);
            packed[j] = SENT;
        } else {
            int bin;
            if (ye) bin = 256 + ((py != 0) ? 32 : 0) + (px >> 5);  // edge seg
            else    bin = py >> 2;                                 // 4-row band
            atomicAdd(&s_hist[bin], 1u);
            packed[j] = ((unsigned)bin << 12) | ((unsigned)(py & 3) << 10)
                      | (unsigned)px;
        }
    }
    __syncthreads();                                               // B2

    // hierarchical exclusive scan of s_hist[0..511]
    const unsigned h = s_hist[t];
    unsigned incl = h;
#pragma unroll
    for (int off = 1; off < 64; off <<= 1) {
        const unsigned n = __shfl_up(incl, off, 64);
        if (lane >= off) incl += n;
    }
    if (lane == 63) s_wsum[wave] = incl;   // wave total
    __syncthreads();                                               // B3
    unsigned woff = 0;
#pragma unroll
    for (int w = 0; w < 8; ++w) woff += (w < wave) ? s_wsum[w] : 0u;
    const unsigned excl = woff + incl - h;

    if (t < NBINS) s_cur[t] = excl;
    if (t <= NBINS)                        // transposed write: [b][bin][chunk]
        prefixT[((size_t)(b * PF_E + t)) * CHUNKS_PER_B + chunk] = excl;
    if (t < 12) {                          // fold 8 wave corner slots
        float s = 0.0f;
#pragma unroll
        for (int w = 0; w < 8; ++w) s += s_corner[w * 12 + t];
        corner_out[blk * 12 + t] = s;
    }
    __syncthreads();                                               // B4

    // cur-ordered scatter into LDS staging (scattered ds_write_b128: cheap)
#pragma unroll
    for (int j = 0; j < 4; ++j) {
        if (packed[j] != SENT) {
            const int bin = packed[j] >> 12;
            const unsigned p = atomicAdd(&s_cur[bin], 1u);
            s_stage[p] = make_float4(__uint_as_float(packed[j]), R[j], G[j], B[j]);
        }
    }
    __syncthreads();                                               // B5

    // fully coalesced LDS -> global copy (1KB per wave per step)
    float4* pbase = staged + (size_t)blk * PTS_PER_CHUNK;
#pragma unroll
    for (int k = 0; k < 4; ++k)
        pbase[k * 512 + t] = s_stage[k * 512 + t];
}

// ---------------------------------------------------------------------------
// K2 @ 1024 threads: 16-wave blocks, 49KB LDS -> 2 blocks/CU = 32 waves/CU
// (hardware wave cap, vs 24 at 512thr) for maximum latency hiding of the
// gather loads. launch_bounds(1024,8) targets VGPR<=64 (kernel needs ~40).
// Gather: 8 consecutive lanes per chunk -> 128B contiguous per iteration,
// ~4 iterations/lane. Store: exactly one float4 per thread per channel.
// Edge blocks (first 256) reuse the same geometry with all 1024 threads.
// ---------------------------------------------------------------------------
__global__ void __launch_bounds__(1024, 8)
render_kernel(const float4* __restrict__ staged, const unsigned* __restrict__ prefixT,
              const float* __restrict__ corner_out, float* __restrict__ out) {
    const int t = threadIdx.x;

    __shared__ float    acc[3 * 4096];     // bands: [c][ly*1024+px]; edge: first 96
    __shared__ unsigned rs[128], re[128];
    float4* acc4 = (float4*)acc;

    if (blockIdx.x < EDGE_BLOCKS) {
        const int blk = blockIdx.x;        // b*64 + row*32 + seg
        const int b   = blk >> 6;
        const int row = (blk >> 5) & 1;
        const int seg = blk & 31;
        const int bin = 256 + row * 32 + seg;

        if (t < 96) acc[t] = 0.0f;
        if (t < 128)      rs[t]       = prefixT[((size_t)(b * PF_E + bin)) * 128 + t];
        else if (t < 256) re[t - 128] = prefixT[((size_t)(b * PF_E + bin + 1)) * 128 + (t - 128)];
        __syncthreads();

        const int chunk = t >> 3;          // 8 lanes per chunk
        const int sub   = t & 7;
        const float4* pbase = staged + (size_t)(b * 128 + chunk) * PTS_PER_CHUNK;
        for (unsigned i = rs[chunk] + sub; i < re[chunk]; i += 8) {
            const float4 v = pbase[i];
            const int lx = (int)(__float_as_uint(v.x) & 1023u) - seg * 32;
            atomicAdd(&acc[lx],      v.y);
            atomicAdd(&acc[32 + lx], v.z);
            atomicAdd(&acc[64 + lx], v.w);
        }

        // corner fold: seg 0 owns px=0, seg 31 owns px=1023 of this row
        if (((seg == 0) | (seg == 31)) & (t < 128)) {
            const int ci = row * 2 + ((seg == 31) ? 1 : 0);
            const int lx = (seg == 31) ? 31 : 0;
            const float* cp = corner_out + (size_t)(b * 128 + t) * 12 + ci * 3;
            atomicAdd(&acc[lx],      cp[0]);
            atomicAdd(&acc[32 + lx], cp[1]);
            atomicAdd(&acc[64 + lx], cp[2]);
        }
        __syncthreads();

        if (t < 96) {                      // write final output row directly
            const int c  = t >> 5, lx = t & 31;
            const size_t py = row ? (IMG_W - 1) : 0;
            const float v = acc[c * 32 + lx];
            out[((size_t)b * 3 + c) * IMG_HW + py * IMG_W + seg * 32 + lx] =
                fminf(fmaxf(v, 0.f), 1.f);
        }
        return;
    }

    const int bg   = blockIdx.x - EDGE_BLOCKS;   // 0..1023
    const int b    = bg >> 8;
    const int band = bg & 255;

    const float4 z4 = make_float4(0.f, 0.f, 0.f, 0.f);
#pragma unroll
    for (int i = 0; i < 3; ++i) acc4[i * 1024 + t] = z4;
    if (t < 128)      rs[t]       = prefixT[((size_t)(b * PF_E + band)) * 128 + t];
    else if (t < 256) re[t - 128] = prefixT[((size_t)(b * PF_E + band + 1)) * 128 + (t - 128)];
    __syncthreads();

    const int chunk = t >> 3;              // 8 consecutive lanes share a chunk
    const int sub   = t & 7;
    const float4* pbase = staged + (size_t)(b * 128 + chunk) * PTS_PER_CHUNK;
    for (unsigned i = rs[chunk] + sub; i < re[chunk]; i += 8) {
        const float4 v = pbase[i];
        const unsigned key = __float_as_uint(v.x);
        const unsigned idx = ((key >> 10) & 3u) * 1024 + (key & 1023u);
        atomicAdd(&acc[idx],        v.y);
        atomicAdd(&acc[4096 + idx], v.z);
        atomicAdd(&acc[8192 + idx], v.w);
    }
    __syncthreads();

    // linear clipped nontemporal stores; band 0 skips row0, band 255 skips
    // row 1023 (those rows are owned by the edge blocks).
    float* ob = out + (size_t)b * 3 * IMG_HW + (size_t)band * 4096;
    const int skip_ly = (band == 0) ? 0 : ((band == 255) ? 3 : -1);
    const bool do_store = ((t >> 8) != skip_ly);   // wave-uniform (256-thr rows)
#pragma unroll
    for (int c = 0; c < 3; ++c) {
        if (do_store) {
            float4 v = acc4[c * 1024 + t];
            nfloat4 w;
            w.x = fminf(fmaxf(v.x, 0.f), 1.f);
            w.y = fminf(fmaxf(v.y, 0.f), 1.f);
            w.z = fminf(fmaxf(v.z, 0.f), 1.f);
            w.w = fminf(fmaxf(v.w, 0.f), 1.f);
            __builtin_nontemporal_store(w, &((nfloat4*)(ob + (size_t)c * IMG_HW))[t]);
        }
    }
}

extern "C" void kernel_launch(void* const* d_in, const int* in_sizes, int n_in,
                              void* d_out, int out_size, void* d_ws, size_t ws_size,
                              hipStream_t stream) {
    const float* uv  = (const float*)d_in[0];   // (4,14,512,512)
    const float* pos = (const float*)d_in[1];   // (4,3,512,512)
    float* out = (float*)d_out;                 // (4,3,1024,1024)

    char* ws = (char*)d_ws;
    float4*   staged     = (float4*)(ws);
    unsigned* prefixT    = (unsigned*)(ws + PF_OFF);
    float*    corner_out = (float*)(ws + CO_OFF);

    bin_kernel   <<<K1_BLOCKS, 512, 0, stream>>>(uv, pos, staged, prefixT,
                                                 corner_out);
    render_kernel<<<EDGE_BLOCKS + BAND_BLOCKS, 1024, 0, stream>>>(staged, prefixT,
                                                                  corner_out, out);
}

// Round 6
// 124.993 us; speedup vs baseline: 2.2839x; 1.0005x over previous
//
#include <hip/hip_runtime.h>

// Problem constants
#define SRC_N   (512 * 512)
#define IMG_W   1024
#define IMG_HW  (1024 * 1024)
#define BATCH   4

#define CHUNKS_PER_B   128
#define K1_BLOCKS      (BATCH * CHUNKS_PER_B)    // 512
#define PTS_PER_CHUNK  2048
// Bins: 0..255 = 4-row bands (y-interior pixels); 256..287 = row-0 px-segments
// (32 px each); 288..319 = row-1023 px-segments. Corners -> LDS side path.
#define NBINS          320
#define PF_E           (NBINS + 1)
#define SENT           0xFFFFFFFFu

#define EDGE_BLOCKS    (BATCH * 64)              // 256 edge jobs
#define BAND_BLOCKS    (BATCH * 256)             // 1024 band jobs

typedef float nfloat4 __attribute__((ext_vector_type(4)));

__device__ __forceinline__ nfloat4 ntload4(const float* p) {
    return __builtin_nontemporal_load((const nfloat4*)p);
}

// ws layout
#define STAGED_BYTES ((size_t)K1_BLOCKS * PTS_PER_CHUNK * 16)          // 16 MB
#define PF_OFF       STAGED_BYTES
#define PF_BYTES     ((size_t)BATCH * PF_E * CHUNKS_PER_B * 4)         // 657 KB
#define CO_OFF       ((PF_OFF + PF_BYTES + 255) & ~(size_t)255)
#define CO_BYTES     ((size_t)K1_BLOCKS * 12 * 4)                      // 24 KB

// ---------------------------------------------------------------------------
// K1: classify + per-chunk bin (proven structure). NEW: copy only the `total`
// valid staged entries (corners excluded, ~23% of slots skipped) -> ~7.6MB
// less staged write+read traffic. Stale slots beyond `total` are never read
// by K2 (runs are bounded by the prefix table).
// ---------------------------------------------------------------------------
__global__ void __launch_bounds__(512, 4)
bin_kernel(const float* __restrict__ uv, const float* __restrict__ pos,
           float4* __restrict__ staged, unsigned* __restrict__ prefixT,
           float* __restrict__ corner_out) {
    const int blk   = blockIdx.x;          // 0..511
    const int b     = blk >> 7;
    const int chunk = blk & (CHUNKS_PER_B - 1);
    const int t     = threadIdx.x;
    const int lane  = t & 63;
    const int wave  = t >> 6;              // 0..7

    __shared__ unsigned s_hist[512];       // bins 320..511 stay zero
    __shared__ unsigned s_cur[NBINS];
    __shared__ unsigned s_wsum[8];
    __shared__ float    s_corner[96];      // [wave][ci*3+c]
    __shared__ float4   s_stage[PTS_PER_CHUNK];   // 32KB bin-sorted staging

    s_hist[t] = 0;
    if (t < 96) s_corner[t] = 0.0f;
    __syncthreads();                                               // B1

    const float* uvb = uv  + (size_t)b * 14 * SRC_N;
    const float* pb  = pos + (size_t)b * 3  * SRC_N;
    const int n0 = chunk * PTS_PER_CHUNK + t * 4;

    // nontemporal: inputs are read exactly once; keep L2 for the staged buf
    const nfloat4 pxv = ntload4(&pb [n0]);
    const nfloat4 pyv = ntload4(&pb [SRC_N + n0]);
    const nfloat4 ux  = ntload4(&uvb[n0]);
    const nfloat4 uy  = ntload4(&uvb[SRC_N + n0]);
    const nfloat4 ov  = ntload4(&uvb[10 * SRC_N + n0]);
    const nfloat4 rv  = ntload4(&uvb[11 * SRC_N + n0]);
    const nfloat4 gv  = ntload4(&uvb[12 * SRC_N + n0]);
    const nfloat4 bv  = ntload4(&uvb[13 * SRC_N + n0]);

    const float X[4]  = {pxv.x + ux.x, pxv.y + ux.y, pxv.z + ux.z, pxv.w + ux.w};
    const float Y[4]  = {pyv.x + uy.x, pyv.y + uy.y, pyv.z + uy.z, pyv.w + uy.w};
    const float O[4]  = {ov.x, ov.y, ov.z, ov.w};
    const float CR[4] = {rv.x, rv.y, rv.z, rv.w};
    const float CG[4] = {gv.x, gv.y, gv.z, gv.w};
    const float CB[4] = {bv.x, bv.y, bv.z, bv.w};

    unsigned packed[4];
    float R[4], G[4], B[4];

#pragma unroll
    for (int j = 0; j < 4; ++j) {
        // truncating cast (matches .astype(int32)), then clamp
        int px = (int)((X[j] + 1.0f) * 512.0f);
        int py = (int)((Y[j] + 1.0f) * 512.0f);
        px = min(max(px, 0), IMG_W - 1);
        py = min(max(py, 0), IMG_W - 1);

        const float opac = 1.0f / (1.0f + __expf(-O[j]));
        R[j] = CR[j] * opac; G[j] = CG[j] * opac; B[j] = CB[j] * opac;

        const bool xe = (px == 0) | (px == IMG_W - 1);
        const bool ye = (py == 0) | (py == IMG_W - 1);
        if (xe & ye) {
            const int ci = ((py != 0) ? 2 : 0) + ((px != 0) ? 1 : 0);
            const int base = wave * 12 + ci * 3;
            atomicAdd(&s_corner[base + 0], R[j]);
            atomicAdd(&s_corner[base + 1], G[j]);
            atomicAdd(&s_corner[base + 2], B[j]);
            packed[j] = SENT;
        } else {
            int bin;
            if (ye) bin = 256 + ((py != 0) ? 32 : 0) + (px >> 5);  // edge seg
            else    bin = py >> 2;                                 // 4-row band
            atomicAdd(&s_hist[bin], 1u);
            packed[j] = ((unsigned)bin << 12) | ((unsigned)(py & 3) << 10)
                      | (unsigned)px;
        }
    }
    __syncthreads();                                               // B2

    // hierarchical exclusive scan of s_hist[0..511]
    const unsigned h = s_hist[t];
    unsigned incl = h;
#pragma unroll
    for (int off = 1; off < 64; off <<= 1) {
        const unsigned n = __shfl_up(incl, off, 64);
        if (lane >= off) incl += n;
    }
    if (lane == 63) s_wsum[wave] = incl;   // wave total
    __syncthreads();                                               // B3
    unsigned woff = 0, total_all = 0;
#pragma unroll
    for (int w = 0; w < 8; ++w) {
        const unsigned ws = s_wsum[w];
        woff      += (w < wave) ? ws : 0u;
        total_all += ws;                   // grand total (valid staged count)
    }
    const unsigned excl = woff + incl - h;

    if (t < NBINS) s_cur[t] = excl;
    if (t <= NBINS)                        // transposed write: [b][bin][chunk]
        prefixT[((size_t)(b * PF_E + t)) * CHUNKS_PER_B + chunk] = excl;
    if (t < 12) {                          // fold 8 wave corner slots
        float s = 0.0f;
#pragma unroll
        for (int w = 0; w < 8; ++w) s += s_corner[w * 12 + t];
        corner_out[blk * 12 + t] = s;
    }
    __syncthreads();                                               // B4

    // cur-ordered scatter into LDS staging (scattered ds_write_b128: cheap)
#pragma unroll
    for (int j = 0; j < 4; ++j) {
        if (packed[j] != SENT) {
            const int bin = packed[j] >> 12;
            const unsigned p = atomicAdd(&s_cur[bin], 1u);
            s_stage[p] = make_float4(__uint_as_float(packed[j]), R[j], G[j], B[j]);
        }
    }
    __syncthreads();                                               // B5

    // coalesced LDS -> global copy of ONLY the valid entries (~77%)
    float4* pbase = staged + (size_t)blk * PTS_PER_CHUNK;
    for (unsigned idx = t; idx < total_all; idx += 512)
        pbase[idx] = s_stage[idx];
}

// ---------------------------------------------------------------------------
// K2 @ 1024 threads (2 blocks/CU = 32 waves/CU). NEW: (a) rs/re hoisted into
// registers (LDS atomics alias-block compiler hoisting), (b) per-lane channel
// rotation (t%3) spreads same-pixel atomic triples over 3 distinct addresses,
// cutting same-address serialization ~3x on the clamped hot columns
// (px=0/1023 receive ~24% of all points).
// ---------------------------------------------------------------------------
__global__ void __launch_bounds__(1024, 8)
render_kernel(const float4* __restrict__ staged, const unsigned* __restrict__ prefixT,
              const float* __restrict__ corner_out, float* __restrict__ out) {
    const int t = threadIdx.x;

    __shared__ float    acc[3 * 4096];     // bands: [c][ly*1024+px]; edge: first 96
    __shared__ unsigned rs[128], re[128];
    float4* acc4 = (float4*)acc;

    if (blockIdx.x < EDGE_BLOCKS) {
        const int blk = blockIdx.x;        // b*64 + row*32 + seg
        const int b   = blk >> 6;
        const int row = (blk >> 5) & 1;
        const int seg = blk & 31;
        const int bin = 256 + row * 32 + seg;

        if (t < 96) acc[t] = 0.0f;
        if (t < 128)      rs[t]       = prefixT[((size_t)(b * PF_E + bin)) * 128 + t];
        else if (t < 256) re[t - 128] = prefixT[((size_t)(b * PF_E + bin + 1)) * 128 + (t - 128)];
        __syncthreads();

        const int chunk = t >> 3;          // 8 lanes per chunk
        const int sub   = t & 7;
        const unsigned ib = rs[chunk] + sub;   // hoist: LDS reads once
        const unsigned ie = re[chunk];
        const float4* pbase = staged + (size_t)(b * 128 + chunk) * PTS_PER_CHUNK;
        for (unsigned i = ib; i < ie; i += 8) {
            const float4 v = pbase[i];
            const int lx = (int)(__float_as_uint(v.x) & 1023u) - seg * 32;
            atomicAdd(&acc[lx],      v.y);
            atomicAdd(&acc[32 + lx], v.z);
            atomicAdd(&acc[64 + lx], v.w);
        }

        // corner fold: seg 0 owns px=0, seg 31 owns px=1023 of this row
        if (((seg == 0) | (seg == 31)) & (t < 128)) {
            const int ci = row * 2 + ((seg == 31) ? 1 : 0);
            const int lx = (seg == 31) ? 31 : 0;
            const float* cp = corner_out + (size_t)(b * 128 + t) * 12 + ci * 3;
            atomicAdd(&acc[lx],      cp[0]);
            atomicAdd(&acc[32 + lx], cp[1]);
            atomicAdd(&acc[64 + lx], cp[2]);
        }
        __syncthreads();

        if (t < 96) {                      // write final output row directly
            const int c  = t >> 5, lx = t & 31;
            const size_t py = row ? (IMG_W - 1) : 0;
            const float v = acc[c * 32 + lx];
            out[((size_t)b * 3 + c) * IMG_HW + py * IMG_W + seg * 32 + lx] =
                fminf(fmaxf(v, 0.f), 1.f);
        }
        return;
    }

    const int bg   = blockIdx.x - EDGE_BLOCKS;   // 0..1023
    const int b    = bg >> 8;
    const int band = bg & 255;

    const float4 z4 = make_float4(0.f, 0.f, 0.f, 0.f);
#pragma unroll
    for (int i = 0; i < 3; ++i) acc4[i * 1024 + t] = z4;
    if (t < 128)      rs[t]       = prefixT[((size_t)(b * PF_E + band)) * 128 + t];
    else if (t < 256) re[t - 128] = prefixT[((size_t)(b * PF_E + band + 1)) * 128 + (t - 128)];
    __syncthreads();

    const int chunk = t >> 3;              // 8 consecutive lanes share a chunk
    const int sub   = t & 7;
    const int rot   = t % 3;               // per-lane channel rotation
    const unsigned ib = rs[chunk] + sub;   // hoist: LDS reads once
    const unsigned ie = re[chunk];
    const float4* pbase = staged + (size_t)(b * 128 + chunk) * PTS_PER_CHUNK;
    for (unsigned i = ib; i < ie; i += 8) {
        const float4 v = pbase[i];
        const unsigned key = __float_as_uint(v.x);
        const unsigned idx = ((key >> 10) & 3u) * 1024 + (key & 1023u);
#pragma unroll
        for (int s = 0; s < 3; ++s) {
            int c = rot + s; c = (c >= 3) ? c - 3 : c;          // cndmask, no mem
            const float vc = (c == 0) ? v.y : ((c == 1) ? v.z : v.w);
            atomicAdd(&acc[(unsigned)c * 4096u + idx], vc);
        }
    }
    __syncthreads();

    // linear clipped nontemporal stores; band 0 skips row0, band 255 skips
    // row 1023 (those rows are owned by the edge blocks).
    float* ob = out + (size_t)b * 3 * IMG_HW + (size_t)band * 4096;
    const int skip_ly = (band == 0) ? 0 : ((band == 255) ? 3 : -1);
    const bool do_store = ((t >> 8) != skip_ly);   // wave-uniform (256-thr rows)
#pragma unroll
    for (int c = 0; c < 3; ++c) {
        if (do_store) {
            float4 v = acc4[c * 1024 + t];
            nfloat4 w;
            w.x = fminf(fmaxf(v.x, 0.f), 1.f);
            w.y = fminf(fmaxf(v.y, 0.f), 1.f);
            w.z = fminf(fmaxf(v.z, 0.f), 1.f);
            w.w = fminf(fmaxf(v.w, 0.f), 1.f);
            __builtin_nontemporal_store(w, &((nfloat4*)(ob + (size_t)c * IMG_HW))[t]);
        }
    }
}

extern "C" void kernel_launch(void* const* d_in, const int* in_sizes, int n_in,
                              void* d_out, int out_size, void* d_ws, size_t ws_size,
                              hipStream_t stream) {
    const float* uv  = (const float*)d_in[0];   // (4,14,512,512)
    const float* pos = (const float*)d_in[1];   // (4,3,512,512)
    float* out = (float*)d_out;                 // (4,3,1024,1024)

    char* ws = (char*)d_ws;
    float4*   staged     = (float4*)(ws);
    unsigned* prefixT    = (unsigned*)(ws + PF_OFF);
    float*    corner_out = (float*)(ws + CO_OFF);

    bin_kernel   <<<K1_BLOCKS, 512, 0, stream>>>(uv, pos, staged, prefixT,
                                                 corner_out);
    render_kernel<<<EDGE_BLOCKS + BAND_BLOCKS, 1024, 0, stream>>>(staged, prefixT,
                                                                  corner_out, out);
}